// Round 2
// baseline (319.870 us; speedup 1.0000x reference)
//
#include <hip/hip_runtime.h>
#include <math.h>

#define NEG_SLOPE 0.2f
#define EPSV 1e-16f
#define NPART 8

typedef _Float16 half4 __attribute__((ext_vector_type(4)));
typedef _Float16 half8 __attribute__((ext_vector_type(8)));
typedef float floatx2 __attribute__((ext_vector_type(2)));

// ---------------- CSR build ----------------

// block scan over 1024-node chunks; deg computed inline from degp; bsum = raw chunk sum
__global__ void k_scan_blk(const int* __restrict__ degp, int N,
                           int* __restrict__ rowptr, int* __restrict__ bsum){
    int b = blockIdx.x, t = threadIdx.x;
    int base = b * 1024 + t * 4;
    int v[4];
    #pragma unroll
    for (int j = 0; j < 4; j++){
        int n = base + j, s = 0;
        if (n < N){
            #pragma unroll
            for (int p = 0; p < NPART; p++) s += degp[p * N + n];
        }
        v[j] = s;
    }
    int s = v[0] + v[1] + v[2] + v[3];
    int lane = t & 63, wid = t >> 6;
    int x = s;
    #pragma unroll
    for (int off = 1; off < 64; off <<= 1){
        int y = __shfl_up(x, off, 64);
        if (lane >= off) x += y;
    }
    __shared__ int ws[4];
    if (lane == 63) ws[wid] = x;
    __syncthreads();
    int woff = 0;
    for (int w = 0; w < wid; w++) woff += ws[w];
    int run = woff + x - s;
    #pragma unroll
    for (int j = 0; j < 4; j++){
        if (base + j < N) rowptr[base + j] = run;
        run += v[j];
    }
    if (t == 255) bsum[b] = woff + x;
}

// rowptr += prefix(bsum); poff[p][n] = rowptr[n] + prefix_p(degp[.][n])
__global__ void k_finalize(const int* __restrict__ bsum, const int* __restrict__ degp,
                           int N, int ET,
                           int* __restrict__ rowptr, int* __restrict__ poff){
    int b = blockIdx.x, t = threadIdx.x;
    int n = b * 256 + t;
    int chunk = (b * 256) >> 10;           // wave-uniform
    int off = 0;
    for (int c = 0; c < chunk; c++) off += bsum[c];
    if (n < N){
        int r = rowptr[n] + off;
        rowptr[n] = r;
        int run = r;
        #pragma unroll
        for (int p = 0; p < NPART; p++){
            poff[p * N + n] = run;
            run += degp[p * N + n];
        }
    }
    if (n == 0) rowptr[N] = ET;
}

// atomic-free scatter (src only; dst implicit via rowptr ranges); partition packed in rank[15:13]
__launch_bounds__(256)
__global__ void k_scatter2(const int* __restrict__ ei, int E, int ET, int N,
                           const int* __restrict__ poff,
                           const unsigned short* __restrict__ rank,
                           int* __restrict__ csr_src){
    int i = blockIdx.x * 256 + threadIdx.x;
    if (i >= ET) return;
    int s, d;
    if (i < E){ s = ei[i]; d = ei[E + i]; } else { s = i - E; d = s; }
    int pr = rank[i];
    int p = pr >> 13, r = pr & 0x1FFF;
    csr_src[poff[p * N + d] + r] = s;
}

// ---------------- Fused: GEMM1 (blocks [0,nGemmBlk)) + hist_rank (rest) ----------------
// GEMM: 64-node tile, W1 chunk held in registers (L2-direct), single barrier per block.
// Hist: partition = physical XCD (XCC_ID), workgroup-scope atomics -> per-XCD L2 RMW.
// LDS 32KB x 5 blocks = 160KB (full CU); VGPR 52 fits 5 waves/SIMD.

__launch_bounds__(256, 5)
__global__ void k_gemm1_hist(const float* __restrict__ x, const float* __restrict__ W1,
                             const float* __restrict__ a_src, const float* __restrict__ a_dst,
                             _Float16* __restrict__ h1h, float* __restrict__ asrc1,
                             float* __restrict__ adst1, int N, int nGemmBlk,
                             const int* __restrict__ ei, int E, int ET,
                             unsigned int* __restrict__ degp, unsigned short* __restrict__ rank){
    __shared__ float xl[64 * 128];    // 32 KB
    int t = threadIdx.x;
    if ((int)blockIdx.x >= nGemmBlk){
        // ---- histogram + rank part: 1024 edges/block, 4 per thread ----
        int p = __builtin_amdgcn_s_getreg((3 << 11) | 20) & 7;   // HW_REG_XCC_ID
        int base = (blockIdx.x - nGemmBlk) * 1024 + t;
        #pragma unroll
        for (int j = 0; j < 4; j++){
            int i = base + j * 256;
            if (i < ET){
                int d = (i < E) ? ei[E + i] : (i - E);   // self loops appended
                unsigned r = __hip_atomic_fetch_add(&degp[(size_t)p * N + d], 1u,
                                 __ATOMIC_RELAXED, __HIP_MEMORY_SCOPE_WORKGROUP);
                rank[i] = (unsigned short)((p << 13) | r);
            }
        }
        return;
    }
    // ---- gemm1 part: 64 nodes x 128 cols; thread = 8 rows (stride 8) x 4 cols ----
    int cg = t & 31, rs = t >> 5;
    int n0 = blockIdx.x * 64;
    for (int idx = t; idx < 2048; idx += 256){
        int row = idx >> 5, k4 = idx & 31;
        float4 v = {0.f, 0.f, 0.f, 0.f};
        if (n0 + row < N) v = *(const float4*)&x[(size_t)(n0 + row) * 128 + k4 * 4];
        *(float4*)&xl[row * 128 + k4 * 4] = v;
    }
    __syncthreads();
    float4 acc[8];
    #pragma unroll
    for (int j = 0; j < 8; j++) acc[j] = (float4){0.f, 0.f, 0.f, 0.f};
    for (int hc = 0; hc < 16; hc++){
        float4 wr[8];
        #pragma unroll
        for (int k = 0; k < 8; k++)
            wr[k] = *(const float4*)&W1[(hc * 8 + k) * 128 + cg * 4];
        #pragma unroll
        for (int kb = 0; kb < 8; kb += 4){
            float4 xv[8];
            #pragma unroll
            for (int j = 0; j < 8; j++)
                xv[j] = *(const float4*)&xl[(rs + 8 * j) * 128 + hc * 8 + kb];
            #pragma unroll
            for (int kk = 0; kk < 4; kk++){
                float4 w = wr[kb + kk];
                #pragma unroll
                for (int j = 0; j < 8; j++){
                    float xs = ((const float*)&xv[j])[kk];
                    acc[j].x = fmaf(xs, w.x, acc[j].x);
                    acc[j].y = fmaf(xs, w.y, acc[j].y);
                    acc[j].z = fmaf(xs, w.z, acc[j].z);
                    acc[j].w = fmaf(xs, w.w, acc[j].w);
                }
            }
        }
    }
    float4 a4s = *(const float4*)&a_src[cg * 4];
    float4 a4d = *(const float4*)&a_dst[cg * 4];
    #pragma unroll
    for (int j = 0; j < 8; j++){
        int n = n0 + rs + 8 * j;
        if (n >= N) continue;
        float4 a = acc[j];
        half4 hv;
        hv.x = (_Float16)a.x; hv.y = (_Float16)a.y;
        hv.z = (_Float16)a.z; hv.w = (_Float16)a.w;
        *(half4*)&h1h[((size_t)n << 7) + (cg << 2)] = hv;
        float vs = a.x * a4s.x + a.y * a4s.y + a.z * a4s.z + a.w * a4s.w;
        float vd = a.x * a4d.x + a.y * a4d.y + a.z * a4d.z + a.w * a4d.w;
        #pragma unroll
        for (int m = 1; m <= 4; m <<= 1){
            vs += __shfl_xor(vs, m, 64);
            vd += __shfl_xor(vd, m, 64);
        }
        if ((cg & 7) == 0){
            int head = cg >> 3;
            asrc1[n * 4 + head] = vs;
            adst1[n * 4 + head] = vd;
        }
    }
}

// ---------------- Aggregation L1: wave/node, 4x16 lanes, unroll-4 (4 gather chains) ------

__launch_bounds__(256)
__global__ void k_agg1(const int* __restrict__ rowptr, const int* __restrict__ csr_src,
                       const float* __restrict__ asrc1, const float* __restrict__ adst1,
                       const _Float16* __restrict__ h1h,
                       const float* __restrict__ b1, float* __restrict__ x2){
    int t = threadIdx.x;
    int n = blockIdx.x * 4 + (t >> 6);
    int lane = t & 63, g = lane >> 4, l = lane & 15, head = l >> 2;
    int start = rowptr[n], end = rowptr[n + 1];
    float adn = adst1[(n << 2) + head];
    const char* hb = (const char*)h1h;
    const char* ab = (const char*)asrc1;
    int hoff = l << 4;
    int aoff = head << 2;
    floatx2 r0[4], r1[4], r2[4], r3[4];
    #pragma unroll
    for (int j = 0; j < 4; j++){
        r0[j] = (floatx2)0.f; r1[j] = (floatx2)0.f;
        r2[j] = (floatx2)0.f; r3[j] = (floatx2)0.f;
    }
    float s0a = 0.f, s1a = 0.f, s2a = 0.f, s3a = 0.f;
    int i = start + g;
    for (; i + 12 < end; i += 16){
        int sa = csr_src[i];
        int sb = csr_src[i + 4];
        int sc = csr_src[i + 8];
        int sd = csr_src[i + 12];
        float ea = *(const float*)(ab + (sa << 4) + aoff) + adn;
        float eb = *(const float*)(ab + (sb << 4) + aoff) + adn;
        float ec = *(const float*)(ab + (sc << 4) + aoff) + adn;
        float ed = *(const float*)(ab + (sd << 4) + aoff) + adn;
        ea = fmaxf(ea, NEG_SLOPE * ea);
        eb = fmaxf(eb, NEG_SLOPE * eb);
        ec = fmaxf(ec, NEG_SLOPE * ec);
        ed = fmaxf(ed, NEG_SLOPE * ed);
        float wa = __expf(ea);
        float wb = __expf(eb);
        float wc = __expf(ec);
        float wd = __expf(ed);
        half8 ha = *(const half8*)(hb + (sa << 8) + hoff);
        half8 hbv = *(const half8*)(hb + (sb << 8) + hoff);
        half8 hcv = *(const half8*)(hb + (sc << 8) + hoff);
        half8 hdv = *(const half8*)(hb + (sd << 8) + hoff);
        s0a += wa; s1a += wb; s2a += wc; s3a += wd;
        floatx2 wa2 = {wa, wa}, wb2 = {wb, wb}, wc2 = {wc, wc}, wd2 = {wd, wd};
        #pragma unroll
        for (int j = 0; j < 4; j++){
            floatx2 ca = {(float)ha[2*j], (float)ha[2*j+1]};
            floatx2 cb = {(float)hbv[2*j], (float)hbv[2*j+1]};
            floatx2 cc = {(float)hcv[2*j], (float)hcv[2*j+1]};
            floatx2 cd = {(float)hdv[2*j], (float)hdv[2*j+1]};
            r0[j] = wa2 * ca + r0[j];      // v_pk_fma_f32
            r1[j] = wb2 * cb + r1[j];
            r2[j] = wc2 * cc + r2[j];
            r3[j] = wd2 * cd + r3[j];
        }
    }
    for (; i < end; i += 4){
        int sa = csr_src[i];
        float ea = *(const float*)(ab + (sa << 4) + aoff) + adn;
        ea = fmaxf(ea, NEG_SLOPE * ea);
        float wa = __expf(ea);
        half8 ha = *(const half8*)(hb + (sa << 8) + hoff);
        s0a += wa;
        floatx2 wa2 = {wa, wa};
        #pragma unroll
        for (int j = 0; j < 4; j++){
            floatx2 ca = {(float)ha[2*j], (float)ha[2*j+1]};
            r0[j] = wa2 * ca + r0[j];
        }
    }
    float r[9];
    #pragma unroll
    for (int j = 0; j < 4; j++){
        floatx2 c = (r0[j] + r1[j]) + (r2[j] + r3[j]);
        r[2*j] = c.x; r[2*j+1] = c.y;
    }
    r[8] = (s0a + s1a) + (s2a + s3a);
    #pragma unroll
    for (int m = 16; m <= 32; m <<= 1)
        #pragma unroll
        for (int j = 0; j < 9; j++) r[j] += __shfl_xor(r[j], m, 64);
    if (g == 0){
        float inv = 1.f / (r[8] + EPSV);
        float o[8];
        #pragma unroll
        for (int j = 0; j < 8; j++){
            float v = r[j] * inv + b1[l * 8 + j];
            o[j] = (v > 0.f) ? v : expm1f(v);   // ELU fused
        }
        float4 o0 = {o[0], o[1], o[2], o[3]};
        float4 o1 = {o[4], o[5], o[6], o[7]};
        *(float4*)&x2[((size_t)n << 7) + (l << 3)]     = o0;
        *(float4*)&x2[((size_t)n << 7) + (l << 3) + 4] = o1;
    }
}

// ---------------- GEMM2: 64-node tile, 48 KB LDS (3 blocks/CU), 2-node blocking ----------

__launch_bounds__(256)
__global__ void k_gemm2(const float* __restrict__ x2, const float* __restrict__ W2,
                        const float* __restrict__ a_src, const float* __restrict__ a_dst,
                        _Float16* __restrict__ h2h, float* __restrict__ asrc2,
                        float* __restrict__ adst2, int N){
    __shared__ float Wl[128 * 32];    // 16 KB
    __shared__ float xl[64 * 128];    // 32 KB
    int t = threadIdx.x;
    int cg = t & 7, ns = t >> 3;      // ns in 0..31
    for (int idx = t; idx < 1024; idx += 256)
        *(float4*)&Wl[idx * 4] = *(const float4*)&W2[idx * 4];
    int n0 = blockIdx.x * 64;
    for (int idx = t; idx < 2048; idx += 256){
        int row = idx >> 5, k4 = idx & 31;
        float4 v = {0.f, 0.f, 0.f, 0.f};
        if (n0 + row < N) v = *(const float4*)&x2[(size_t)(n0 + row) * 128 + k4 * 4];
        *(float4*)&xl[row * 128 + k4 * 4] = v;
    }
    __syncthreads();
    float4 acc0 = {0,0,0,0}, acc1 = {0,0,0,0};
    #pragma unroll 2
    for (int k = 0; k < 128; k += 4){
        float4 xv0 = *(float4*)&xl[(ns      ) * 128 + k];
        float4 xv1 = *(float4*)&xl[(ns + 32) * 128 + k];
        #pragma unroll
        for (int kk = 0; kk < 4; kk++){
            float4 w = *(float4*)&Wl[(k + kk) * 32 + cg * 4];
            float x0 = ((float*)&xv0)[kk];
            float x1 = ((float*)&xv1)[kk];
            acc0.x = fmaf(x0, w.x, acc0.x); acc0.y = fmaf(x0, w.y, acc0.y);
            acc0.z = fmaf(x0, w.z, acc0.z); acc0.w = fmaf(x0, w.w, acc0.w);
            acc1.x = fmaf(x1, w.x, acc1.x); acc1.y = fmaf(x1, w.y, acc1.y);
            acc1.z = fmaf(x1, w.z, acc1.z); acc1.w = fmaf(x1, w.w, acc1.w);
        }
    }
    float4 a4s = *(const float4*)&a_src[cg * 4];
    float4 a4d = *(const float4*)&a_dst[cg * 4];
    float4 accs[2] = {acc0, acc1};
    #pragma unroll
    for (int j = 0; j < 2; j++){
        int n = n0 + ns + 32 * j;
        if (n >= N) continue;
        float4 a = accs[j];
        half4 hv;
        hv.x = (_Float16)a.x; hv.y = (_Float16)a.y;
        hv.z = (_Float16)a.z; hv.w = (_Float16)a.w;
        *(half4*)&h2h[((size_t)n << 5) + (cg << 2)] = hv;
        float vs = a.x * a4s.x + a.y * a4s.y + a.z * a4s.z + a.w * a4s.w;
        float vd = a.x * a4d.x + a.y * a4d.y + a.z * a4d.z + a.w * a4d.w;
        #pragma unroll
        for (int m = 1; m <= 4; m <<= 1){
            vs += __shfl_xor(vs, m, 64);
            vd += __shfl_xor(vd, m, 64);
        }
        if (cg == 0){ asrc2[n] = vs; adst2[n] = vd; }
    }
}

// ---------------- Aggregation L2: 2 nodes/wave, 4 groups x 8 lanes, unroll-4 -------------

__launch_bounds__(256)
__global__ void k_agg2(const int* __restrict__ rowptr, const int* __restrict__ csr_src,
                       const float* __restrict__ asrc2, const float* __restrict__ adst2,
                       const _Float16* __restrict__ h2h,
                       const float* __restrict__ b2, float* __restrict__ out){
    int t = threadIdx.x;
    int n = blockIdx.x * 8 + (t >> 5);
    int l5 = t & 31, g = l5 >> 3, l = l5 & 7;
    int start = rowptr[n], end = rowptr[n + 1];
    float adn = adst2[n];
    const char* hb = (const char*)h2h;
    const char* ab = (const char*)asrc2;
    int hoff = l << 3;
    floatx2 a0[2], a1[2], a2[2], a3[2];
    a0[0] = (floatx2)0.f; a0[1] = (floatx2)0.f;
    a1[0] = (floatx2)0.f; a1[1] = (floatx2)0.f;
    a2[0] = (floatx2)0.f; a2[1] = (floatx2)0.f;
    a3[0] = (floatx2)0.f; a3[1] = (floatx2)0.f;
    float s0a = 0.f, s1a = 0.f, s2a = 0.f, s3a = 0.f;
    int i = start + g;
    for (; i + 12 < end; i += 16){
        int sa = csr_src[i];
        int sb = csr_src[i + 4];
        int sc = csr_src[i + 8];
        int sd = csr_src[i + 12];
        float ea = *(const float*)(ab + (sa << 2)) + adn;
        float eb = *(const float*)(ab + (sb << 2)) + adn;
        float ec = *(const float*)(ab + (sc << 2)) + adn;
        float ed = *(const float*)(ab + (sd << 2)) + adn;
        ea = fmaxf(ea, NEG_SLOPE * ea);
        eb = fmaxf(eb, NEG_SLOPE * eb);
        ec = fmaxf(ec, NEG_SLOPE * ec);
        ed = fmaxf(ed, NEG_SLOPE * ed);
        float wa = __expf(ea);
        float wb = __expf(eb);
        float wc = __expf(ec);
        float wd = __expf(ed);
        half4 ha = *(const half4*)(hb + (sa << 6) + hoff);
        half4 hbv = *(const half4*)(hb + (sb << 6) + hoff);
        half4 hcv = *(const half4*)(hb + (sc << 6) + hoff);
        half4 hdv = *(const half4*)(hb + (sd << 6) + hoff);
        s0a += wa; s1a += wb; s2a += wc; s3a += wd;
        floatx2 wa2 = {wa, wa}, wb2 = {wb, wb}, wc2 = {wc, wc}, wd2 = {wd, wd};
        floatx2 ca0 = {(float)ha.x, (float)ha.y},  ca1 = {(float)ha.z, (float)ha.w};
        floatx2 cb0 = {(float)hbv.x, (float)hbv.y}, cb1 = {(float)hbv.z, (float)hbv.w};
        floatx2 cc0 = {(float)hcv.x, (float)hcv.y}, cc1 = {(float)hcv.z, (float)hcv.w};
        floatx2 cd0 = {(float)hdv.x, (float)hdv.y}, cd1 = {(float)hdv.z, (float)hdv.w};
        a0[0] = wa2 * ca0 + a0[0]; a0[1] = wa2 * ca1 + a0[1];
        a1[0] = wb2 * cb0 + a1[0]; a1[1] = wb2 * cb1 + a1[1];
        a2[0] = wc2 * cc0 + a2[0]; a2[1] = wc2 * cc1 + a2[1];
        a3[0] = wd2 * cd0 + a3[0]; a3[1] = wd2 * cd1 + a3[1];
    }
    for (; i < end; i += 4){
        int sa = csr_src[i];
        float ea = *(const float*)(ab + (sa << 2)) + adn;
        ea = fmaxf(ea, NEG_SLOPE * ea);
        float wa = __expf(ea);
        half4 ha = *(const half4*)(hb + (sa << 6) + hoff);
        s0a += wa;
        floatx2 wa2 = {wa, wa};
        floatx2 ca0 = {(float)ha.x, (float)ha.y}, ca1 = {(float)ha.z, (float)ha.w};
        a0[0] = wa2 * ca0 + a0[0]; a0[1] = wa2 * ca1 + a0[1];
    }
    floatx2 m0 = (a0[0] + a1[0]) + (a2[0] + a3[0]);
    floatx2 m1 = (a0[1] + a1[1]) + (a2[1] + a3[1]);
    float4 acc = {m0.x, m0.y, m1.x, m1.y};
    float ssum = (s0a + s1a) + (s2a + s3a);
    #pragma unroll
    for (int m = 8; m <= 16; m <<= 1){
        acc.x += __shfl_xor(acc.x, m, 64);
        acc.y += __shfl_xor(acc.y, m, 64);
        acc.z += __shfl_xor(acc.z, m, 64);
        acc.w += __shfl_xor(acc.w, m, 64);
        ssum  += __shfl_xor(ssum,  m, 64);
    }
    if (g == 0){
        float inv = 1.f / (ssum + EPSV);
        const float4 b4 = *(const float4*)&b2[l * 4];
        float4 o;
        o.x = acc.x * inv + b4.x; o.y = acc.y * inv + b4.y;
        o.z = acc.z * inv + b4.z; o.w = acc.w * inv + b4.w;
        *(float4*)&out[((size_t)n << 5) + l * 4] = o;
    }
}

// ---------------- launch ----------------

extern "C" void kernel_launch(void* const* d_in, const int* in_sizes, int n_in,
                              void* d_out, int out_size, void* d_ws, size_t ws_size,
                              hipStream_t stream){
    const float* x      = (const float*)d_in[0];
    const int*   ei     = (const int*)  d_in[1];
    const float* W1     = (const float*)d_in[2];
    const float* a_src1 = (const float*)d_in[3];
    const float* a_dst1 = (const float*)d_in[4];
    const float* b1     = (const float*)d_in[5];
    const float* W2     = (const float*)d_in[6];
    const float* a_src2 = (const float*)d_in[7];
    const float* a_dst2 = (const float*)d_in[8];
    const float* b2     = (const float*)d_in[9];
    float* out = (float*)d_out;

    int N  = in_sizes[0] / 128;
    int E  = in_sizes[1] / 2;
    int ET = E + N;
    int nScanBlk = (N + 1023) / 1024;
    int G  = (ET + 255) / 256;
    int GH = (ET + 1023) / 1024;
    int nGemmBlk = (N + 63) / 64;

    char* ws = (char*)d_ws;
    size_t off = 0;
    auto alloc = [&](size_t bytes) -> char* {
        char* p = ws + off;
        off += (bytes + 255) & ~(size_t)255;
        return p;
    };
    int*            degp    = (int*)           alloc((size_t)NPART * N * 4);
    int*            rowptr  = (int*)           alloc((size_t)(N + 1) * 4);
    int*            bsum    = (int*)           alloc((size_t)nScanBlk * 4);
    unsigned short* rank    = (unsigned short*)alloc((size_t)ET * 2);
    int*            poff    = (int*)           alloc((size_t)NPART * N * 4);
    int*            csr_src = (int*)           alloc((size_t)ET * 4);
    _Float16*       h1h     = (_Float16*)      alloc((size_t)N * 128 * 2);
    float*          x2      = (float*)         alloc((size_t)N * 128 * 4);
    float*          asrc1   = (float*)         alloc((size_t)N * 4 * 4);
    float*          adst1   = (float*)         alloc((size_t)N * 4 * 4);
    _Float16*       h2h     = (_Float16*)      alloc((size_t)N * 32 * 2);
    float*          asrc2   = (float*)         alloc((size_t)N * 4);
    float*          adst2   = (float*)         alloc((size_t)N * 4);

    hipMemsetAsync(degp, 0, (size_t)NPART * N * 4, stream);
    hipLaunchKernelGGL(k_gemm1_hist, dim3(nGemmBlk + GH), dim3(256), 0, stream,
                       x, W1, a_src1, a_dst1, h1h, asrc1, adst1, N, nGemmBlk,
                       ei, E, ET, (unsigned int*)degp, rank);
    hipLaunchKernelGGL(k_scan_blk,  dim3(nScanBlk), dim3(256), 0, stream, degp, N, rowptr, bsum);
    hipLaunchKernelGGL(k_finalize,  dim3((N + 255) / 256), dim3(256), 0, stream, bsum, degp, N, ET, rowptr, poff);
    hipLaunchKernelGGL(k_scatter2,  dim3(G), dim3(256), 0, stream, ei, E, ET, N, poff, rank, csr_src);
    hipLaunchKernelGGL(k_agg1,      dim3(N / 4), dim3(256), 0, stream, rowptr, csr_src, asrc1, adst1, h1h, b1, x2);
    hipLaunchKernelGGL(k_gemm2,     dim3((N + 63) / 64), dim3(256), 0, stream, x2, W2, a_src2, a_dst2, h2h, asrc2, adst2, N);
    hipLaunchKernelGGL(k_agg2,      dim3(N / 8), dim3(256), 0, stream, rowptr, csr_src, asrc2, adst2, h2h, b2, out);
}

// Round 3
// 301.861 us; speedup vs baseline: 1.0597x; 1.0597x over previous
//
#include <hip/hip_runtime.h>
#include <math.h>

#define NEG_SLOPE 0.2f
#define EPSV 1e-16f
#define NPART 8

typedef _Float16 half4 __attribute__((ext_vector_type(4)));
typedef _Float16 half8 __attribute__((ext_vector_type(8)));
typedef float floatx2 __attribute__((ext_vector_type(2)));

// ---------------- CSR build ----------------

// block scan over 1024-node chunks; deg computed inline from degp; bsum = raw chunk sum
__global__ void k_scan_blk(const int* __restrict__ degp, int N,
                           int* __restrict__ rowptr, int* __restrict__ bsum){
    int b = blockIdx.x, t = threadIdx.x;
    int base = b * 1024 + t * 4;
    int v[4];
    #pragma unroll
    for (int j = 0; j < 4; j++){
        int n = base + j, s = 0;
        if (n < N){
            #pragma unroll
            for (int p = 0; p < NPART; p++) s += degp[p * N + n];
        }
        v[j] = s;
    }
    int s = v[0] + v[1] + v[2] + v[3];
    int lane = t & 63, wid = t >> 6;
    int x = s;
    #pragma unroll
    for (int off = 1; off < 64; off <<= 1){
        int y = __shfl_up(x, off, 64);
        if (lane >= off) x += y;
    }
    __shared__ int ws[4];
    if (lane == 63) ws[wid] = x;
    __syncthreads();
    int woff = 0;
    for (int w = 0; w < wid; w++) woff += ws[w];
    int run = woff + x - s;
    #pragma unroll
    for (int j = 0; j < 4; j++){
        if (base + j < N) rowptr[base + j] = run;
        run += v[j];
    }
    if (t == 255) bsum[b] = woff + x;
}

// rowptr += prefix(bsum); poff[p][n] = rowptr[n] + prefix_p(degp[.][n])
__global__ void k_finalize(const int* __restrict__ bsum, const int* __restrict__ degp,
                           int N, int ET,
                           int* __restrict__ rowptr, int* __restrict__ poff){
    int b = blockIdx.x, t = threadIdx.x;
    int n = b * 256 + t;
    int chunk = (b * 256) >> 10;           // wave-uniform
    int off = 0;
    for (int c = 0; c < chunk; c++) off += bsum[c];
    if (n < N){
        int r = rowptr[n] + off;
        rowptr[n] = r;
        int run = r;
        #pragma unroll
        for (int p = 0; p < NPART; p++){
            poff[p * N + n] = run;
            run += degp[p * N + n];
        }
    }
    if (n == 0) rowptr[N] = ET;
}

// atomic-free scatter (src only; dst implicit via rowptr ranges); partition packed in rank[15:13]
__launch_bounds__(256)
__global__ void k_scatter2(const int* __restrict__ ei, int E, int ET, int N,
                           const int* __restrict__ poff,
                           const unsigned short* __restrict__ rank,
                           int* __restrict__ csr_src){
    int i = blockIdx.x * 256 + threadIdx.x;
    if (i >= ET) return;
    int s, d;
    if (i < E){ s = ei[i]; d = ei[E + i]; } else { s = i - E; d = s; }
    int pr = rank[i];
    int p = pr >> 13, r = pr & 0x1FFF;
    csr_src[poff[p * N + d] + r] = s;
}

// ---------------- Fused: GEMM1 (blocks [0,nGemmBlk)) + hist_rank (rest) ----------------
// GEMM: 64-node tile, W1 chunk held in registers (L2-direct), single barrier per block.
// Hist: partition = physical XCD (XCC_ID), workgroup-scope atomics -> per-XCD L2 RMW.
// LDS 32KB x 5 blocks = 160KB (full CU); VGPR 52 fits 5 waves/SIMD.

__launch_bounds__(256, 5)
__global__ void k_gemm1_hist(const float* __restrict__ x, const float* __restrict__ W1,
                             const float* __restrict__ a_src, const float* __restrict__ a_dst,
                             _Float16* __restrict__ h1h, float* __restrict__ asrc1,
                             float* __restrict__ adst1, int N, int nGemmBlk,
                             const int* __restrict__ ei, int E, int ET,
                             unsigned int* __restrict__ degp, unsigned short* __restrict__ rank){
    __shared__ float xl[64 * 128];    // 32 KB
    int t = threadIdx.x;
    if ((int)blockIdx.x >= nGemmBlk){
        // ---- histogram + rank part: 1024 edges/block, 4 per thread ----
        int p = __builtin_amdgcn_s_getreg((3 << 11) | 20) & 7;   // HW_REG_XCC_ID
        int base = (blockIdx.x - nGemmBlk) * 1024 + t;
        #pragma unroll
        for (int j = 0; j < 4; j++){
            int i = base + j * 256;
            if (i < ET){
                int d = (i < E) ? ei[E + i] : (i - E);   // self loops appended
                unsigned r = __hip_atomic_fetch_add(&degp[(size_t)p * N + d], 1u,
                                 __ATOMIC_RELAXED, __HIP_MEMORY_SCOPE_WORKGROUP);
                rank[i] = (unsigned short)((p << 13) | r);
            }
        }
        return;
    }
    // ---- gemm1 part: 64 nodes x 128 cols; thread = 8 rows (stride 8) x 4 cols ----
    int cg = t & 31, rs = t >> 5;
    int n0 = blockIdx.x * 64;
    for (int idx = t; idx < 2048; idx += 256){
        int row = idx >> 5, k4 = idx & 31;
        float4 v = {0.f, 0.f, 0.f, 0.f};
        if (n0 + row < N) v = *(const float4*)&x[(size_t)(n0 + row) * 128 + k4 * 4];
        *(float4*)&xl[row * 128 + k4 * 4] = v;
    }
    __syncthreads();
    float4 acc[8];
    #pragma unroll
    for (int j = 0; j < 8; j++) acc[j] = (float4){0.f, 0.f, 0.f, 0.f};
    for (int hc = 0; hc < 16; hc++){
        float4 wr[8];
        #pragma unroll
        for (int k = 0; k < 8; k++)
            wr[k] = *(const float4*)&W1[(hc * 8 + k) * 128 + cg * 4];
        #pragma unroll
        for (int kb = 0; kb < 8; kb += 4){
            float4 xv[8];
            #pragma unroll
            for (int j = 0; j < 8; j++)
                xv[j] = *(const float4*)&xl[(rs + 8 * j) * 128 + hc * 8 + kb];
            #pragma unroll
            for (int kk = 0; kk < 4; kk++){
                float4 w = wr[kb + kk];
                #pragma unroll
                for (int j = 0; j < 8; j++){
                    float xs = ((const float*)&xv[j])[kk];
                    acc[j].x = fmaf(xs, w.x, acc[j].x);
                    acc[j].y = fmaf(xs, w.y, acc[j].y);
                    acc[j].z = fmaf(xs, w.z, acc[j].z);
                    acc[j].w = fmaf(xs, w.w, acc[j].w);
                }
            }
        }
    }
    float4 a4s = *(const float4*)&a_src[cg * 4];
    float4 a4d = *(const float4*)&a_dst[cg * 4];
    #pragma unroll
    for (int j = 0; j < 8; j++){
        int n = n0 + rs + 8 * j;
        if (n >= N) continue;
        float4 a = acc[j];
        half4 hv;
        hv.x = (_Float16)a.x; hv.y = (_Float16)a.y;
        hv.z = (_Float16)a.z; hv.w = (_Float16)a.w;
        *(half4*)&h1h[((size_t)n << 7) + (cg << 2)] = hv;
        float vs = a.x * a4s.x + a.y * a4s.y + a.z * a4s.z + a.w * a4s.w;
        float vd = a.x * a4d.x + a.y * a4d.y + a.z * a4d.z + a.w * a4d.w;
        #pragma unroll
        for (int m = 1; m <= 4; m <<= 1){
            vs += __shfl_xor(vs, m, 64);
            vd += __shfl_xor(vd, m, 64);
        }
        if ((cg & 7) == 0){
            int head = cg >> 3;
            asrc1[n * 4 + head] = vs;
            adst1[n * 4 + head] = vd;
        }
    }
}

// ---------------- Aggregation L1: GROUP-PER-NODE. 16 lanes own one node, walk its whole
// edge list stride-1 with 4 independent gather chains. No cross-group reduction. ---------

__launch_bounds__(256)
__global__ void k_agg1(const int* __restrict__ rowptr, const int* __restrict__ csr_src,
                       const float* __restrict__ asrc1, const float* __restrict__ adst1,
                       const _Float16* __restrict__ h1h,
                       const float* __restrict__ b1, float* __restrict__ x2, int N){
    int t = threadIdx.x;
    int lane = t & 63;
    int g = lane >> 4, l = lane & 15, head = l >> 2;
    int n = blockIdx.x * 16 + ((t >> 6) << 2) + g;
    bool valid = (n < N);
    int nn = valid ? n : 0;
    int start = rowptr[nn], end = rowptr[nn + 1];
    float adn = adst1[(nn << 2) + head];
    const char* hb = (const char*)h1h;
    const char* ab = (const char*)asrc1;
    int hoff = l << 4;
    int aoff = head << 2;
    floatx2 r0[4], r1[4], r2[4], r3[4];
    #pragma unroll
    for (int j = 0; j < 4; j++){
        r0[j] = (floatx2)0.f; r1[j] = (floatx2)0.f;
        r2[j] = (floatx2)0.f; r3[j] = (floatx2)0.f;
    }
    float s0a = 0.f, s1a = 0.f, s2a = 0.f, s3a = 0.f;
    int i = start;
    for (; i + 3 < end; i += 4){
        int sa = csr_src[i];
        int sb = csr_src[i + 1];
        int sc = csr_src[i + 2];
        int sd = csr_src[i + 3];
        float ea = *(const float*)(ab + (sa << 4) + aoff) + adn;
        float eb = *(const float*)(ab + (sb << 4) + aoff) + adn;
        float ec = *(const float*)(ab + (sc << 4) + aoff) + adn;
        float ed = *(const float*)(ab + (sd << 4) + aoff) + adn;
        ea = fmaxf(ea, NEG_SLOPE * ea);
        eb = fmaxf(eb, NEG_SLOPE * eb);
        ec = fmaxf(ec, NEG_SLOPE * ec);
        ed = fmaxf(ed, NEG_SLOPE * ed);
        float wa = __expf(ea);
        float wb = __expf(eb);
        float wc = __expf(ec);
        float wd = __expf(ed);
        half8 ha = *(const half8*)(hb + (sa << 8) + hoff);
        half8 hbv = *(const half8*)(hb + (sb << 8) + hoff);
        half8 hcv = *(const half8*)(hb + (sc << 8) + hoff);
        half8 hdv = *(const half8*)(hb + (sd << 8) + hoff);
        s0a += wa; s1a += wb; s2a += wc; s3a += wd;
        floatx2 wa2 = {wa, wa}, wb2 = {wb, wb}, wc2 = {wc, wc}, wd2 = {wd, wd};
        #pragma unroll
        for (int j = 0; j < 4; j++){
            floatx2 ca = {(float)ha[2*j], (float)ha[2*j+1]};
            floatx2 cb = {(float)hbv[2*j], (float)hbv[2*j+1]};
            floatx2 cc = {(float)hcv[2*j], (float)hcv[2*j+1]};
            floatx2 cd = {(float)hdv[2*j], (float)hdv[2*j+1]};
            r0[j] = wa2 * ca + r0[j];      // v_pk_fma_f32
            r1[j] = wb2 * cb + r1[j];
            r2[j] = wc2 * cc + r2[j];
            r3[j] = wd2 * cd + r3[j];
        }
    }
    for (; i < end; i++){
        int sa = csr_src[i];
        float ea = *(const float*)(ab + (sa << 4) + aoff) + adn;
        ea = fmaxf(ea, NEG_SLOPE * ea);
        float wa = __expf(ea);
        half8 ha = *(const half8*)(hb + (sa << 8) + hoff);
        s0a += wa;
        floatx2 wa2 = {wa, wa};
        #pragma unroll
        for (int j = 0; j < 4; j++){
            floatx2 ca = {(float)ha[2*j], (float)ha[2*j+1]};
            r0[j] = wa2 * ca + r0[j];
        }
    }
    if (valid){
        float ssum = (s0a + s1a) + (s2a + s3a);
        float inv = 1.f / (ssum + EPSV);
        float o[8];
        #pragma unroll
        for (int j = 0; j < 4; j++){
            floatx2 c = (r0[j] + r1[j]) + (r2[j] + r3[j]);
            float v0 = c.x * inv + b1[l * 8 + 2*j];
            float v1 = c.y * inv + b1[l * 8 + 2*j + 1];
            o[2*j]   = (v0 > 0.f) ? v0 : expm1f(v0);   // ELU fused
            o[2*j+1] = (v1 > 0.f) ? v1 : expm1f(v1);
        }
        float4 o0 = {o[0], o[1], o[2], o[3]};
        float4 o1 = {o[4], o[5], o[6], o[7]};
        *(float4*)&x2[((size_t)n << 7) + (l << 3)]     = o0;
        *(float4*)&x2[((size_t)n << 7) + (l << 3) + 4] = o1;
    }
}

// ---------------- GEMM2: 64-node tile, 48 KB LDS (3 blocks/CU), 2-node blocking ----------

__launch_bounds__(256)
__global__ void k_gemm2(const float* __restrict__ x2, const float* __restrict__ W2,
                        const float* __restrict__ a_src, const float* __restrict__ a_dst,
                        _Float16* __restrict__ h2h, float* __restrict__ asrc2,
                        float* __restrict__ adst2, int N){
    __shared__ float Wl[128 * 32];    // 16 KB
    __shared__ float xl[64 * 128];    // 32 KB
    int t = threadIdx.x;
    int cg = t & 7, ns = t >> 3;      // ns in 0..31
    for (int idx = t; idx < 1024; idx += 256)
        *(float4*)&Wl[idx * 4] = *(const float4*)&W2[idx * 4];
    int n0 = blockIdx.x * 64;
    for (int idx = t; idx < 2048; idx += 256){
        int row = idx >> 5, k4 = idx & 31;
        float4 v = {0.f, 0.f, 0.f, 0.f};
        if (n0 + row < N) v = *(const float4*)&x2[(size_t)(n0 + row) * 128 + k4 * 4];
        *(float4*)&xl[row * 128 + k4 * 4] = v;
    }
    __syncthreads();
    float4 acc0 = {0,0,0,0}, acc1 = {0,0,0,0};
    #pragma unroll 2
    for (int k = 0; k < 128; k += 4){
        float4 xv0 = *(float4*)&xl[(ns      ) * 128 + k];
        float4 xv1 = *(float4*)&xl[(ns + 32) * 128 + k];
        #pragma unroll
        for (int kk = 0; kk < 4; kk++){
            float4 w = *(float4*)&Wl[(k + kk) * 32 + cg * 4];
            float x0 = ((float*)&xv0)[kk];
            float x1 = ((float*)&xv1)[kk];
            acc0.x = fmaf(x0, w.x, acc0.x); acc0.y = fmaf(x0, w.y, acc0.y);
            acc0.z = fmaf(x0, w.z, acc0.z); acc0.w = fmaf(x0, w.w, acc0.w);
            acc1.x = fmaf(x1, w.x, acc1.x); acc1.y = fmaf(x1, w.y, acc1.y);
            acc1.z = fmaf(x1, w.z, acc1.z); acc1.w = fmaf(x1, w.w, acc1.w);
        }
    }
    float4 a4s = *(const float4*)&a_src[cg * 4];
    float4 a4d = *(const float4*)&a_dst[cg * 4];
    float4 accs[2] = {acc0, acc1};
    #pragma unroll
    for (int j = 0; j < 2; j++){
        int n = n0 + ns + 32 * j;
        if (n >= N) continue;
        float4 a = accs[j];
        half4 hv;
        hv.x = (_Float16)a.x; hv.y = (_Float16)a.y;
        hv.z = (_Float16)a.z; hv.w = (_Float16)a.w;
        *(half4*)&h2h[((size_t)n << 5) + (cg << 2)] = hv;
        float vs = a.x * a4s.x + a.y * a4s.y + a.z * a4s.z + a.w * a4s.w;
        float vd = a.x * a4d.x + a.y * a4d.y + a.z * a4d.z + a.w * a4d.w;
        #pragma unroll
        for (int m = 1; m <= 4; m <<= 1){
            vs += __shfl_xor(vs, m, 64);
            vd += __shfl_xor(vd, m, 64);
        }
        if (cg == 0){ asrc2[n] = vs; adst2[n] = vd; }
    }
}

// ---------------- Aggregation L2: GROUP-PER-NODE. 8 lanes own one node. -----------------

__launch_bounds__(256)
__global__ void k_agg2(const int* __restrict__ rowptr, const int* __restrict__ csr_src,
                       const float* __restrict__ asrc2, const float* __restrict__ adst2,
                       const _Float16* __restrict__ h2h,
                       const float* __restrict__ b2, float* __restrict__ out, int N){
    int t = threadIdx.x;
    int lane = t & 63;
    int g = lane >> 3, l = lane & 7;
    int n = blockIdx.x * 32 + ((t >> 6) << 3) + g;
    bool valid = (n < N);
    int nn = valid ? n : 0;
    int start = rowptr[nn], end = rowptr[nn + 1];
    float adn = adst2[nn];
    const char* hb = (const char*)h2h;
    const char* ab = (const char*)asrc2;
    int hoff = l << 3;
    floatx2 a0[2], a1[2], a2[2], a3[2];
    a0[0] = (floatx2)0.f; a0[1] = (floatx2)0.f;
    a1[0] = (floatx2)0.f; a1[1] = (floatx2)0.f;
    a2[0] = (floatx2)0.f; a2[1] = (floatx2)0.f;
    a3[0] = (floatx2)0.f; a3[1] = (floatx2)0.f;
    float s0a = 0.f, s1a = 0.f, s2a = 0.f, s3a = 0.f;
    int i = start;
    for (; i + 3 < end; i += 4){
        int sa = csr_src[i];
        int sb = csr_src[i + 1];
        int sc = csr_src[i + 2];
        int sd = csr_src[i + 3];
        float ea = *(const float*)(ab + (sa << 2)) + adn;
        float eb = *(const float*)(ab + (sb << 2)) + adn;
        float ec = *(const float*)(ab + (sc << 2)) + adn;
        float ed = *(const float*)(ab + (sd << 2)) + adn;
        ea = fmaxf(ea, NEG_SLOPE * ea);
        eb = fmaxf(eb, NEG_SLOPE * eb);
        ec = fmaxf(ec, NEG_SLOPE * ec);
        ed = fmaxf(ed, NEG_SLOPE * ed);
        float wa = __expf(ea);
        float wb = __expf(eb);
        float wc = __expf(ec);
        float wd = __expf(ed);
        half4 ha = *(const half4*)(hb + (sa << 6) + hoff);
        half4 hbv = *(const half4*)(hb + (sb << 6) + hoff);
        half4 hcv = *(const half4*)(hb + (sc << 6) + hoff);
        half4 hdv = *(const half4*)(hb + (sd << 6) + hoff);
        s0a += wa; s1a += wb; s2a += wc; s3a += wd;
        floatx2 wa2 = {wa, wa}, wb2 = {wb, wb}, wc2 = {wc, wc}, wd2 = {wd, wd};
        floatx2 ca0 = {(float)ha.x, (float)ha.y},  ca1 = {(float)ha.z, (float)ha.w};
        floatx2 cb0 = {(float)hbv.x, (float)hbv.y}, cb1 = {(float)hbv.z, (float)hbv.w};
        floatx2 cc0 = {(float)hcv.x, (float)hcv.y}, cc1 = {(float)hcv.z, (float)hcv.w};
        floatx2 cd0 = {(float)hdv.x, (float)hdv.y}, cd1 = {(float)hdv.z, (float)hdv.w};
        a0[0] = wa2 * ca0 + a0[0]; a0[1] = wa2 * ca1 + a0[1];
        a1[0] = wb2 * cb0 + a1[0]; a1[1] = wb2 * cb1 + a1[1];
        a2[0] = wc2 * cc0 + a2[0]; a2[1] = wc2 * cc1 + a2[1];
        a3[0] = wd2 * cd0 + a3[0]; a3[1] = wd2 * cd1 + a3[1];
    }
    for (; i < end; i++){
        int sa = csr_src[i];
        float ea = *(const float*)(ab + (sa << 2)) + adn;
        ea = fmaxf(ea, NEG_SLOPE * ea);
        float wa = __expf(ea);
        half4 ha = *(const half4*)(hb + (sa << 6) + hoff);
        s0a += wa;
        floatx2 wa2 = {wa, wa};
        floatx2 ca0 = {(float)ha.x, (float)ha.y}, ca1 = {(float)ha.z, (float)ha.w};
        a0[0] = wa2 * ca0 + a0[0]; a0[1] = wa2 * ca1 + a0[1];
    }
    if (valid){
        floatx2 m0 = (a0[0] + a1[0]) + (a2[0] + a3[0]);
        floatx2 m1 = (a0[1] + a1[1]) + (a2[1] + a3[1]);
        float ssum = (s0a + s1a) + (s2a + s3a);
        float inv = 1.f / (ssum + EPSV);
        const float4 b4 = *(const float4*)&b2[l * 4];
        float4 o;
        o.x = m0.x * inv + b4.x; o.y = m0.y * inv + b4.y;
        o.z = m1.x * inv + b4.z; o.w = m1.y * inv + b4.w;
        *(float4*)&out[((size_t)n << 5) + (l << 2)] = o;
    }
}

// ---------------- launch ----------------

extern "C" void kernel_launch(void* const* d_in, const int* in_sizes, int n_in,
                              void* d_out, int out_size, void* d_ws, size_t ws_size,
                              hipStream_t stream){
    const float* x      = (const float*)d_in[0];
    const int*   ei     = (const int*)  d_in[1];
    const float* W1     = (const float*)d_in[2];
    const float* a_src1 = (const float*)d_in[3];
    const float* a_dst1 = (const float*)d_in[4];
    const float* b1     = (const float*)d_in[5];
    const float* W2     = (const float*)d_in[6];
    const float* a_src2 = (const float*)d_in[7];
    const float* a_dst2 = (const float*)d_in[8];
    const float* b2     = (const float*)d_in[9];
    float* out = (float*)d_out;

    int N  = in_sizes[0] / 128;
    int E  = in_sizes[1] / 2;
    int ET = E + N;
    int nScanBlk = (N + 1023) / 1024;
    int G  = (ET + 255) / 256;
    int GH = (ET + 1023) / 1024;
    int nGemmBlk = (N + 63) / 64;

    char* ws = (char*)d_ws;
    size_t off = 0;
    auto alloc = [&](size_t bytes) -> char* {
        char* p = ws + off;
        off += (bytes + 255) & ~(size_t)255;
        return p;
    };
    int*            degp    = (int*)           alloc((size_t)NPART * N * 4);
    int*            rowptr  = (int*)           alloc((size_t)(N + 1) * 4);
    int*            bsum    = (int*)           alloc((size_t)nScanBlk * 4);
    unsigned short* rank    = (unsigned short*)alloc((size_t)ET * 2);
    int*            poff    = (int*)           alloc((size_t)NPART * N * 4);
    int*            csr_src = (int*)           alloc((size_t)ET * 4);
    _Float16*       h1h     = (_Float16*)      alloc((size_t)N * 128 * 2);
    float*          x2      = (float*)         alloc((size_t)N * 128 * 4);
    float*          asrc1   = (float*)         alloc((size_t)N * 4 * 4);
    float*          adst1   = (float*)         alloc((size_t)N * 4 * 4);
    _Float16*       h2h     = (_Float16*)      alloc((size_t)N * 32 * 2);
    float*          asrc2   = (float*)         alloc((size_t)N * 4);
    float*          adst2   = (float*)         alloc((size_t)N * 4);

    hipMemsetAsync(degp, 0, (size_t)NPART * N * 4, stream);
    hipLaunchKernelGGL(k_gemm1_hist, dim3(nGemmBlk + GH), dim3(256), 0, stream,
                       x, W1, a_src1, a_dst1, h1h, asrc1, adst1, N, nGemmBlk,
                       ei, E, ET, (unsigned int*)degp, rank);
    hipLaunchKernelGGL(k_scan_blk,  dim3(nScanBlk), dim3(256), 0, stream, degp, N, rowptr, bsum);
    hipLaunchKernelGGL(k_finalize,  dim3((N + 255) / 256), dim3(256), 0, stream, bsum, degp, N, ET, rowptr, poff);
    hipLaunchKernelGGL(k_scatter2,  dim3(G), dim3(256), 0, stream, ei, E, ET, N, poff, rank, csr_src);
    hipLaunchKernelGGL(k_agg1,      dim3((N + 15) / 16), dim3(256), 0, stream, rowptr, csr_src, asrc1, adst1, h1h, b1, x2, N);
    hipLaunchKernelGGL(k_gemm2,     dim3((N + 63) / 64), dim3(256), 0, stream, x2, W2, a_src2, a_dst2, h2h, asrc2, adst2, N);
    hipLaunchKernelGGL(k_agg2,      dim3((N + 31) / 32), dim3(256), 0, stream, rowptr, csr_src, asrc2, adst2, h2h, b2, out, N);
}

// Round 4
// 298.680 us; speedup vs baseline: 1.0709x; 1.0106x over previous
//
#include <hip/hip_runtime.h>
#include <math.h>

#define NEG_SLOPE 0.2f
#define EPSV 1e-16f
#define NPART 8

typedef _Float16 half4 __attribute__((ext_vector_type(4)));
typedef _Float16 half8 __attribute__((ext_vector_type(8)));
typedef float floatx2 __attribute__((ext_vector_type(2)));

// ---------------- CSR build ----------------

// block scan over 1024-node chunks; deg computed inline from degp; bsum = raw chunk sum
__global__ void k_scan_blk(const int* __restrict__ degp, int N,
                           int* __restrict__ rowptr, int* __restrict__ bsum){
    int b = blockIdx.x, t = threadIdx.x;
    int base = b * 1024 + t * 4;
    int v[4];
    #pragma unroll
    for (int j = 0; j < 4; j++){
        int n = base + j, s = 0;
        if (n < N){
            #pragma unroll
            for (int p = 0; p < NPART; p++) s += degp[p * N + n];
        }
        v[j] = s;
    }
    int s = v[0] + v[1] + v[2] + v[3];
    int lane = t & 63, wid = t >> 6;
    int x = s;
    #pragma unroll
    for (int off = 1; off < 64; off <<= 1){
        int y = __shfl_up(x, off, 64);
        if (lane >= off) x += y;
    }
    __shared__ int ws[4];
    if (lane == 63) ws[wid] = x;
    __syncthreads();
    int woff = 0;
    for (int w = 0; w < wid; w++) woff += ws[w];
    int run = woff + x - s;
    #pragma unroll
    for (int j = 0; j < 4; j++){
        if (base + j < N) rowptr[base + j] = run;
        run += v[j];
    }
    if (t == 255) bsum[b] = woff + x;
}

// rowptr += prefix(bsum); poff[p][n] = rowptr[n] + prefix_p(degp[.][n])
__global__ void k_finalize(const int* __restrict__ bsum, const int* __restrict__ degp,
                           int N, int ET,
                           int* __restrict__ rowptr, int* __restrict__ poff){
    int b = blockIdx.x, t = threadIdx.x;
    int n = b * 256 + t;
    int chunk = (b * 256) >> 10;           // wave-uniform
    int off = 0;
    for (int c = 0; c < chunk; c++) off += bsum[c];
    if (n < N){
        int r = rowptr[n] + off;
        rowptr[n] = r;
        int run = r;
        #pragma unroll
        for (int p = 0; p < NPART; p++){
            poff[p * N + n] = run;
            run += degp[p * N + n];
        }
    }
    if (n == 0) rowptr[N] = ET;
}

// atomic-free scatter (src only; dst implicit via rowptr ranges); partition packed in rank[15:13]
__launch_bounds__(256)
__global__ void k_scatter2(const int* __restrict__ ei, int E, int ET, int N,
                           const int* __restrict__ poff,
                           const unsigned short* __restrict__ rank,
                           int* __restrict__ csr_src){
    int i = blockIdx.x * 256 + threadIdx.x;
    if (i >= ET) return;
    int s, d;
    if (i < E){ s = ei[i]; d = ei[E + i]; } else { s = i - E; d = s; }
    int pr = rank[i];
    int p = pr >> 13, r = pr & 0x1FFF;
    csr_src[poff[p * N + d] + r] = s;
}

// ---------------- Fused: GEMM1 (blocks [0,nGemmBlk)) + hist_rank (rest) ----------------
// GEMM: 64-node tile; W1 double-buffered in REGISTERS (wrA/wrB) so the L2 load of chunk
// hc+1 is in flight while chunk hc's FMAs run. Forces ~150 VGPR live range (the round-3
// version collapsed to 48 VGPR and serialized every W load at its use point -> 18% VALUBusy).
// Hist: partition = physical XCD (XCC_ID), workgroup-scope atomics -> per-XCD L2 RMW.

#define GEMM1_COMPUTE(HC, WR)                                                   \
    {                                                                           \
        _Pragma("unroll")                                                       \
        for (int kb = 0; kb < 8; kb += 4){                                      \
            float4 xv[8];                                                       \
            _Pragma("unroll")                                                   \
            for (int j = 0; j < 8; j++)                                         \
                xv[j] = *(const float4*)&xl[(rs + 8 * j) * 128 + (HC) * 8 + kb];\
            _Pragma("unroll")                                                   \
            for (int kk = 0; kk < 4; kk++){                                     \
                float4 w = WR[kb + kk];                                         \
                _Pragma("unroll")                                               \
                for (int j = 0; j < 8; j++){                                    \
                    float xs = ((const float*)&xv[j])[kk];                      \
                    acc[j].x = fmaf(xs, w.x, acc[j].x);                         \
                    acc[j].y = fmaf(xs, w.y, acc[j].y);                         \
                    acc[j].z = fmaf(xs, w.z, acc[j].z);                         \
                    acc[j].w = fmaf(xs, w.w, acc[j].w);                         \
                }                                                               \
            }                                                                   \
        }                                                                       \
    }

__launch_bounds__(256, 3)
__global__ void k_gemm1_hist(const float* __restrict__ x, const float* __restrict__ W1,
                             const float* __restrict__ a_src, const float* __restrict__ a_dst,
                             _Float16* __restrict__ h1h, float* __restrict__ asrc1,
                             float* __restrict__ adst1, int N, int nGemmBlk,
                             const int* __restrict__ ei, int E, int ET,
                             unsigned int* __restrict__ degp, unsigned short* __restrict__ rank){
    __shared__ float xl[64 * 128];    // 32 KB
    int t = threadIdx.x;
    if ((int)blockIdx.x >= nGemmBlk){
        // ---- histogram + rank part: 1024 edges/block, 4 per thread ----
        int p = __builtin_amdgcn_s_getreg((3 << 11) | 20) & 7;   // HW_REG_XCC_ID
        int base = (blockIdx.x - nGemmBlk) * 1024 + t;
        #pragma unroll
        for (int j = 0; j < 4; j++){
            int i = base + j * 256;
            if (i < ET){
                int d = (i < E) ? ei[E + i] : (i - E);   // self loops appended
                unsigned r = __hip_atomic_fetch_add(&degp[(size_t)p * N + d], 1u,
                                 __ATOMIC_RELAXED, __HIP_MEMORY_SCOPE_WORKGROUP);
                rank[i] = (unsigned short)((p << 13) | r);
            }
        }
        return;
    }
    // ---- gemm1 part: 64 nodes x 128 cols; thread = 8 rows (stride 8) x 4 cols ----
    int cg = t & 31, rs = t >> 5;
    int n0 = blockIdx.x * 64;
    for (int idx = t; idx < 2048; idx += 256){
        int row = idx >> 5, k4 = idx & 31;
        float4 v = {0.f, 0.f, 0.f, 0.f};
        if (n0 + row < N) v = *(const float4*)&x[(size_t)(n0 + row) * 128 + k4 * 4];
        *(float4*)&xl[row * 128 + k4 * 4] = v;
    }
    __syncthreads();
    float4 acc[8];
    #pragma unroll
    for (int j = 0; j < 8; j++) acc[j] = (float4){0.f, 0.f, 0.f, 0.f};
    const float4* Wv = (const float4*)W1;   // float4 index: row*32 + cg
    float4 wrA[8], wrB[8];
    #pragma unroll
    for (int k = 0; k < 8; k++) wrA[k] = Wv[k * 32 + cg];
    #pragma unroll 1
    for (int hc = 0; hc < 16; hc += 2){
        // prefetch chunk hc+1 while computing chunk hc
        #pragma unroll
        for (int k = 0; k < 8; k++) wrB[k] = Wv[((hc + 1) * 8 + k) * 32 + cg];
        GEMM1_COMPUTE(hc, wrA);
        // prefetch chunk hc+2 while computing chunk hc+1 (wrap harmlessly on last iter)
        int hc2 = (hc + 2 < 16) ? hc + 2 : 0;
        #pragma unroll
        for (int k = 0; k < 8; k++) wrA[k] = Wv[(hc2 * 8 + k) * 32 + cg];
        GEMM1_COMPUTE(hc + 1, wrB);
    }
    float4 a4s = *(const float4*)&a_src[cg * 4];
    float4 a4d = *(const float4*)&a_dst[cg * 4];
    #pragma unroll
    for (int j = 0; j < 8; j++){
        int n = n0 + rs + 8 * j;
        if (n >= N) continue;
        float4 a = acc[j];
        half4 hv;
        hv.x = (_Float16)a.x; hv.y = (_Float16)a.y;
        hv.z = (_Float16)a.z; hv.w = (_Float16)a.w;
        *(half4*)&h1h[((size_t)n << 7) + (cg << 2)] = hv;
        float vs = a.x * a4s.x + a.y * a4s.y + a.z * a4s.z + a.w * a4s.w;
        float vd = a.x * a4d.x + a.y * a4d.y + a.z * a4d.z + a.w * a4d.w;
        #pragma unroll
        for (int m = 1; m <= 4; m <<= 1){
            vs += __shfl_xor(vs, m, 64);
            vd += __shfl_xor(vd, m, 64);
        }
        if ((cg & 7) == 0){
            int head = cg >> 3;
            asrc1[n * 4 + head] = vs;
            adst1[n * 4 + head] = vd;
        }
    }
}

// ---------------- Aggregation L1: GROUP-PER-NODE. 16 lanes own one node, walk its whole
// edge list stride-1 with 4 independent gather chains. No cross-group reduction. ---------

__launch_bounds__(256)
__global__ void k_agg1(const int* __restrict__ rowptr, const int* __restrict__ csr_src,
                       const float* __restrict__ asrc1, const float* __restrict__ adst1,
                       const _Float16* __restrict__ h1h,
                       const float* __restrict__ b1, float* __restrict__ x2, int N){
    int t = threadIdx.x;
    int lane = t & 63;
    int g = lane >> 4, l = lane & 15, head = l >> 2;
    int n = blockIdx.x * 16 + ((t >> 6) << 2) + g;
    bool valid = (n < N);
    int nn = valid ? n : 0;
    int start = rowptr[nn], end = rowptr[nn + 1];
    float adn = adst1[(nn << 2) + head];
    const char* hb = (const char*)h1h;
    const char* ab = (const char*)asrc1;
    int hoff = l << 4;
    int aoff = head << 2;
    floatx2 r0[4], r1[4], r2[4], r3[4];
    #pragma unroll
    for (int j = 0; j < 4; j++){
        r0[j] = (floatx2)0.f; r1[j] = (floatx2)0.f;
        r2[j] = (floatx2)0.f; r3[j] = (floatx2)0.f;
    }
    float s0a = 0.f, s1a = 0.f, s2a = 0.f, s3a = 0.f;
    int i = start;
    for (; i + 3 < end; i += 4){
        int sa = csr_src[i];
        int sb = csr_src[i + 1];
        int sc = csr_src[i + 2];
        int sd = csr_src[i + 3];
        float ea = *(const float*)(ab + (sa << 4) + aoff) + adn;
        float eb = *(const float*)(ab + (sb << 4) + aoff) + adn;
        float ec = *(const float*)(ab + (sc << 4) + aoff) + adn;
        float ed = *(const float*)(ab + (sd << 4) + aoff) + adn;
        ea = fmaxf(ea, NEG_SLOPE * ea);
        eb = fmaxf(eb, NEG_SLOPE * eb);
        ec = fmaxf(ec, NEG_SLOPE * ec);
        ed = fmaxf(ed, NEG_SLOPE * ed);
        float wa = __expf(ea);
        float wb = __expf(eb);
        float wc = __expf(ec);
        float wd = __expf(ed);
        half8 ha = *(const half8*)(hb + (sa << 8) + hoff);
        half8 hbv = *(const half8*)(hb + (sb << 8) + hoff);
        half8 hcv = *(const half8*)(hb + (sc << 8) + hoff);
        half8 hdv = *(const half8*)(hb + (sd << 8) + hoff);
        s0a += wa; s1a += wb; s2a += wc; s3a += wd;
        floatx2 wa2 = {wa, wa}, wb2 = {wb, wb}, wc2 = {wc, wc}, wd2 = {wd, wd};
        #pragma unroll
        for (int j = 0; j < 4; j++){
            floatx2 ca = {(float)ha[2*j], (float)ha[2*j+1]};
            floatx2 cb = {(float)hbv[2*j], (float)hbv[2*j+1]};
            floatx2 cc = {(float)hcv[2*j], (float)hcv[2*j+1]};
            floatx2 cd = {(float)hdv[2*j], (float)hdv[2*j+1]};
            r0[j] = wa2 * ca + r0[j];      // v_pk_fma_f32
            r1[j] = wb2 * cb + r1[j];
            r2[j] = wc2 * cc + r2[j];
            r3[j] = wd2 * cd + r3[j];
        }
    }
    for (; i < end; i++){
        int sa = csr_src[i];
        float ea = *(const float*)(ab + (sa << 4) + aoff) + adn;
        ea = fmaxf(ea, NEG_SLOPE * ea);
        float wa = __expf(ea);
        half8 ha = *(const half8*)(hb + (sa << 8) + hoff);
        s0a += wa;
        floatx2 wa2 = {wa, wa};
        #pragma unroll
        for (int j = 0; j < 4; j++){
            floatx2 ca = {(float)ha[2*j], (float)ha[2*j+1]};
            r0[j] = wa2 * ca + r0[j];
        }
    }
    if (valid){
        float ssum = (s0a + s1a) + (s2a + s3a);
        float inv = 1.f / (ssum + EPSV);
        float o[8];
        #pragma unroll
        for (int j = 0; j < 4; j++){
            floatx2 c = (r0[j] + r1[j]) + (r2[j] + r3[j]);
            float v0 = c.x * inv + b1[l * 8 + 2*j];
            float v1 = c.y * inv + b1[l * 8 + 2*j + 1];
            o[2*j]   = (v0 > 0.f) ? v0 : expm1f(v0);   // ELU fused
            o[2*j+1] = (v1 > 0.f) ? v1 : expm1f(v1);
        }
        float4 o0 = {o[0], o[1], o[2], o[3]};
        float4 o1 = {o[4], o[5], o[6], o[7]};
        *(float4*)&x2[((size_t)n << 7) + (l << 3)]     = o0;
        *(float4*)&x2[((size_t)n << 7) + (l << 3) + 4] = o1;
    }
}

// ---------------- GEMM2: 64-node tile, 48 KB LDS (3 blocks/CU), 2-node blocking ----------

__launch_bounds__(256)
__global__ void k_gemm2(const float* __restrict__ x2, const float* __restrict__ W2,
                        const float* __restrict__ a_src, const float* __restrict__ a_dst,
                        _Float16* __restrict__ h2h, float* __restrict__ asrc2,
                        float* __restrict__ adst2, int N){
    __shared__ float Wl[128 * 32];    // 16 KB
    __shared__ float xl[64 * 128];    // 32 KB
    int t = threadIdx.x;
    int cg = t & 7, ns = t >> 3;      // ns in 0..31
    for (int idx = t; idx < 1024; idx += 256)
        *(float4*)&Wl[idx * 4] = *(const float4*)&W2[idx * 4];
    int n0 = blockIdx.x * 64;
    for (int idx = t; idx < 2048; idx += 256){
        int row = idx >> 5, k4 = idx & 31;
        float4 v = {0.f, 0.f, 0.f, 0.f};
        if (n0 + row < N) v = *(const float4*)&x2[(size_t)(n0 + row) * 128 + k4 * 4];
        *(float4*)&xl[row * 128 + k4 * 4] = v;
    }
    __syncthreads();
    float4 acc0 = {0,0,0,0}, acc1 = {0,0,0,0};
    #pragma unroll 2
    for (int k = 0; k < 128; k += 4){
        float4 xv0 = *(float4*)&xl[(ns      ) * 128 + k];
        float4 xv1 = *(float4*)&xl[(ns + 32) * 128 + k];
        #pragma unroll
        for (int kk = 0; kk < 4; kk++){
            float4 w = *(float4*)&Wl[(k + kk) * 32 + cg * 4];
            float x0 = ((float*)&xv0)[kk];
            float x1 = ((float*)&xv1)[kk];
            acc0.x = fmaf(x0, w.x, acc0.x); acc0.y = fmaf(x0, w.y, acc0.y);
            acc0.z = fmaf(x0, w.z, acc0.z); acc0.w = fmaf(x0, w.w, acc0.w);
            acc1.x = fmaf(x1, w.x, acc1.x); acc1.y = fmaf(x1, w.y, acc1.y);
            acc1.z = fmaf(x1, w.z, acc1.z); acc1.w = fmaf(x1, w.w, acc1.w);
        }
    }
    float4 a4s = *(const float4*)&a_src[cg * 4];
    float4 a4d = *(const float4*)&a_dst[cg * 4];
    float4 accs[2] = {acc0, acc1};
    #pragma unroll
    for (int j = 0; j < 2; j++){
        int n = n0 + ns + 32 * j;
        if (n >= N) continue;
        float4 a = accs[j];
        half4 hv;
        hv.x = (_Float16)a.x; hv.y = (_Float16)a.y;
        hv.z = (_Float16)a.z; hv.w = (_Float16)a.w;
        *(half4*)&h2h[((size_t)n << 5) + (cg << 2)] = hv;
        float vs = a.x * a4s.x + a.y * a4s.y + a.z * a4s.z + a.w * a4s.w;
        float vd = a.x * a4d.x + a.y * a4d.y + a.z * a4d.z + a.w * a4d.w;
        #pragma unroll
        for (int m = 1; m <= 4; m <<= 1){
            vs += __shfl_xor(vs, m, 64);
            vd += __shfl_xor(vd, m, 64);
        }
        if (cg == 0){ asrc2[n] = vs; adst2[n] = vd; }
    }
}

// ---------------- Aggregation L2: GROUP-PER-NODE. 8 lanes own one node. -----------------

__launch_bounds__(256)
__global__ void k_agg2(const int* __restrict__ rowptr, const int* __restrict__ csr_src,
                       const float* __restrict__ asrc2, const float* __restrict__ adst2,
                       const _Float16* __restrict__ h2h,
                       const float* __restrict__ b2, float* __restrict__ out, int N){
    int t = threadIdx.x;
    int lane = t & 63;
    int g = lane >> 3, l = lane & 7;
    int n = blockIdx.x * 32 + ((t >> 6) << 3) + g;
    bool valid = (n < N);
    int nn = valid ? n : 0;
    int start = rowptr[nn], end = rowptr[nn + 1];
    float adn = adst2[nn];
    const char* hb = (const char*)h2h;
    const char* ab = (const char*)asrc2;
    int hoff = l << 3;
    floatx2 a0[2], a1[2], a2[2], a3[2];
    a0[0] = (floatx2)0.f; a0[1] = (floatx2)0.f;
    a1[0] = (floatx2)0.f; a1[1] = (floatx2)0.f;
    a2[0] = (floatx2)0.f; a2[1] = (floatx2)0.f;
    a3[0] = (floatx2)0.f; a3[1] = (floatx2)0.f;
    float s0a = 0.f, s1a = 0.f, s2a = 0.f, s3a = 0.f;
    int i = start;
    for (; i + 3 < end; i += 4){
        int sa = csr_src[i];
        int sb = csr_src[i + 1];
        int sc = csr_src[i + 2];
        int sd = csr_src[i + 3];
        float ea = *(const float*)(ab + (sa << 2)) + adn;
        float eb = *(const float*)(ab + (sb << 2)) + adn;
        float ec = *(const float*)(ab + (sc << 2)) + adn;
        float ed = *(const float*)(ab + (sd << 2)) + adn;
        ea = fmaxf(ea, NEG_SLOPE * ea);
        eb = fmaxf(eb, NEG_SLOPE * eb);
        ec = fmaxf(ec, NEG_SLOPE * ec);
        ed = fmaxf(ed, NEG_SLOPE * ed);
        float wa = __expf(ea);
        float wb = __expf(eb);
        float wc = __expf(ec);
        float wd = __expf(ed);
        half4 ha = *(const half4*)(hb + (sa << 6) + hoff);
        half4 hbv = *(const half4*)(hb + (sb << 6) + hoff);
        half4 hcv = *(const half4*)(hb + (sc << 6) + hoff);
        half4 hdv = *(const half4*)(hb + (sd << 6) + hoff);
        s0a += wa; s1a += wb; s2a += wc; s3a += wd;
        floatx2 wa2 = {wa, wa}, wb2 = {wb, wb}, wc2 = {wc, wc}, wd2 = {wd, wd};
        floatx2 ca0 = {(float)ha.x, (float)ha.y},  ca1 = {(float)ha.z, (float)ha.w};
        floatx2 cb0 = {(float)hbv.x, (float)hbv.y}, cb1 = {(float)hbv.z, (float)hbv.w};
        floatx2 cc0 = {(float)hcv.x, (float)hcv.y}, cc1 = {(float)hcv.z, (float)hcv.w};
        floatx2 cd0 = {(float)hdv.x, (float)hdv.y}, cd1 = {(float)hdv.z, (float)hdv.w};
        a0[0] = wa2 * ca0 + a0[0]; a0[1] = wa2 * ca1 + a0[1];
        a1[0] = wb2 * cb0 + a1[0]; a1[1] = wb2 * cb1 + a1[1];
        a2[0] = wc2 * cc0 + a2[0]; a2[1] = wc2 * cc1 + a2[1];
        a3[0] = wd2 * cd0 + a3[0]; a3[1] = wd2 * cd1 + a3[1];
    }
    for (; i < end; i++){
        int sa = csr_src[i];
        float ea = *(const float*)(ab + (sa << 2)) + adn;
        ea = fmaxf(ea, NEG_SLOPE * ea);
        float wa = __expf(ea);
        half4 ha = *(const half4*)(hb + (sa << 6) + hoff);
        s0a += wa;
        floatx2 wa2 = {wa, wa};
        floatx2 ca0 = {(float)ha.x, (float)ha.y}, ca1 = {(float)ha.z, (float)ha.w};
        a0[0] = wa2 * ca0 + a0[0]; a0[1] = wa2 * ca1 + a0[1];
    }
    if (valid){
        floatx2 m0 = (a0[0] + a1[0]) + (a2[0] + a3[0]);
        floatx2 m1 = (a0[1] + a1[1]) + (a2[1] + a3[1]);
        float ssum = (s0a + s1a) + (s2a + s3a);
        float inv = 1.f / (ssum + EPSV);
        const float4 b4 = *(const float4*)&b2[l * 4];
        float4 o;
        o.x = m0.x * inv + b4.x; o.y = m0.y * inv + b4.y;
        o.z = m1.x * inv + b4.z; o.w = m1.y * inv + b4.w;
        *(float4*)&out[((size_t)n << 5) + (l << 2)] = o;
    }
}

// ---------------- launch ----------------

extern "C" void kernel_launch(void* const* d_in, const int* in_sizes, int n_in,
                              void* d_out, int out_size, void* d_ws, size_t ws_size,
                              hipStream_t stream){
    const float* x      = (const float*)d_in[0];
    const int*   ei     = (const int*)  d_in[1];
    const float* W1     = (const float*)d_in[2];
    const float* a_src1 = (const float*)d_in[3];
    const float* a_dst1 = (const float*)d_in[4];
    const float* b1     = (const float*)d_in[5];
    const float* W2     = (const float*)d_in[6];
    const float* a_src2 = (const float*)d_in[7];
    const float* a_dst2 = (const float*)d_in[8];
    const float* b2     = (const float*)d_in[9];
    float* out = (float*)d_out;

    int N  = in_sizes[0] / 128;
    int E  = in_sizes[1] / 2;
    int ET = E + N;
    int nScanBlk = (N + 1023) / 1024;
    int G  = (ET + 255) / 256;
    int GH = (ET + 1023) / 1024;
    int nGemmBlk = (N + 63) / 64;

    char* ws = (char*)d_ws;
    size_t off = 0;
    auto alloc = [&](size_t bytes) -> char* {
        char* p = ws + off;
        off += (bytes + 255) & ~(size_t)255;
        return p;
    };
    int*            degp    = (int*)           alloc((size_t)NPART * N * 4);
    int*            rowptr  = (int*)           alloc((size_t)(N + 1) * 4);
    int*            bsum    = (int*)           alloc((size_t)nScanBlk * 4);
    unsigned short* rank    = (unsigned short*)alloc((size_t)ET * 2);
    int*            poff    = (int*)           alloc((size_t)NPART * N * 4);
    int*            csr_src = (int*)           alloc((size_t)ET * 4);
    _Float16*       h1h     = (_Float16*)      alloc((size_t)N * 128 * 2);
    float*          x2      = (float*)         alloc((size_t)N * 128 * 4);
    float*          asrc1   = (float*)         alloc((size_t)N * 4 * 4);
    float*          adst1   = (float*)         alloc((size_t)N * 4 * 4);
    _Float16*       h2h     = (_Float16*)      alloc((size_t)N * 32 * 2);
    float*          asrc2   = (float*)         alloc((size_t)N * 4);
    float*          adst2   = (float*)         alloc((size_t)N * 4);

    hipMemsetAsync(degp, 0, (size_t)NPART * N * 4, stream);
    hipLaunchKernelGGL(k_gemm1_hist, dim3(nGemmBlk + GH), dim3(256), 0, stream,
                       x, W1, a_src1, a_dst1, h1h, asrc1, adst1, N, nGemmBlk,
                       ei, E, ET, (unsigned int*)degp, rank);
    hipLaunchKernelGGL(k_scan_blk,  dim3(nScanBlk), dim3(256), 0, stream, degp, N, rowptr, bsum);
    hipLaunchKernelGGL(k_finalize,  dim3((N + 255) / 256), dim3(256), 0, stream, bsum, degp, N, ET, rowptr, poff);
    hipLaunchKernelGGL(k_scatter2,  dim3(G), dim3(256), 0, stream, ei, E, ET, N, poff, rank, csr_src);
    hipLaunchKernelGGL(k_agg1,      dim3((N + 15) / 16), dim3(256), 0, stream, rowptr, csr_src, asrc1, adst1, h1h, b1, x2, N);
    hipLaunchKernelGGL(k_gemm2,     dim3((N + 63) / 64), dim3(256), 0, stream, x2, W2, a_src2, a_dst2, h2h, asrc2, adst2, N);
    hipLaunchKernelGGL(k_agg2,      dim3((N + 31) / 32), dim3(256), 0, stream, rowptr, csr_src, asrc2, adst2, h2h, b2, out, N);
}